// Round 6
// baseline (86.770 us; speedup 1.0000x reference)
//
#include <hip/hip_runtime.h>
#include <hip/hip_bf16.h>
#include <cstdint>
#include <cstddef>

#define PI_F 3.14159265358979323846f
#define TWO_PI_F 6.28318530717958647692f

typedef __bf16 bf16x8 __attribute__((ext_vector_type(8)));
typedef __bf16 bf16x4 __attribute__((ext_vector_type(4)));
typedef float  f32x4  __attribute__((ext_vector_type(4)));

__device__ __forceinline__ __bf16 to_bf16(float f) { return (__bf16)f; }

// global -> LDS async copy, 16B per lane; LDS dest is wave-uniform base + lane*16
#define GLD_LDS16(gsrc, ldst)                                            \
  __builtin_amdgcn_global_load_lds(                                      \
      (const __attribute__((address_space(1))) void*)(gsrc),             \
      (__attribute__((address_space(3))) void*)(ldst), 16, 0, 0)

// ---------------------------------------------------------------------------
// Kernel P: per-(layer,pair) beamsplitter params -> ws table.
// ---------------------------------------------------------------------------
__global__ __launch_bounds__(256) void olk_params(
    const float* __restrict__ theta, const float* __restrict__ phi,
    float4* __restrict__ t4, float2* __restrict__ t2) {
  int idx = blockIdx.x * 256 + threadIdx.x;  // 256*128 = 32768 total
  float t = fmodf(theta[idx], PI_F);
  float p = phi[idx];
  if (t > 0.5f * PI_F) { t = PI_F - t; p += PI_F; }
  p = fmodf(p, TWO_PI_F);
  float c  = cosf(t), s  = sinf(t);
  float cp = cosf(p), sp = sinf(p);
  t4[idx] = make_float4(cp * c, sp * c, cp * s, sp * s);
  t2[idx] = make_float2(c, s);
}

// ---------------------------------------------------------------------------
// Build kernel: V = e_r^T, then V <- V * T_l for l = 255..0.
// Output written in MFMA fragment order (see olk_mm).
// ---------------------------------------------------------------------------
struct P8 {
  float4 qa[8];
  float4 qb[8];
  float4 cc[8];
};

template<bool TBL>
__device__ __forceinline__ void loadP8(P8& P, int lb, int lane,
    const float4* __restrict__ t4, const float2* __restrict__ t2,
    const float* __restrict__ theta, const float* __restrict__ phi) {
  if (TBL) {
#pragma unroll
    for (int k = 0; k < 8; ++k) {
      int idx = (lb + k) * 128 + 2 * lane;
      P.qa[k] = t4[idx];
      P.qb[k] = t4[idx + 1];
      P.cc[k] = *(const float4*)&t2[idx];
    }
  } else {
#pragma unroll
    for (int k = 0; k < 8; ++k) {
      int idx = (lb + k) * 128 + 2 * lane;
      float2 th = *(const float2*)&theta[idx];
      float2 ph = *(const float2*)&phi[idx];
      float ta = fmodf(th.x, PI_F), pa = ph.x;
      if (ta > 0.5f * PI_F) { ta = PI_F - ta; pa += PI_F; }
      pa = fmodf(pa, TWO_PI_F);
      float tb = fmodf(th.y, PI_F), pb = ph.y;
      if (tb > 0.5f * PI_F) { tb = PI_F - tb; pb += PI_F; }
      pb = fmodf(pb, TWO_PI_F);
      float ca = cosf(ta), sa = sinf(ta), cpa = cosf(pa), spa = sinf(pa);
      float cb = cosf(tb), sb = sinf(tb), cpb = cosf(pb), spb = sinf(pb);
      P.qa[k] = make_float4(cpa * ca, spa * ca, cpa * sa, spa * sa);
      P.qb[k] = make_float4(cpb * cb, spb * cb, cpb * sb, spb * sb);
      P.cc[k] = make_float4(ca, sa, cb, sb);
    }
  }
}

__device__ __forceinline__ void layer_step(bool odd, int lane,
    float4 qa, float4 qb, float4 cc,
    float& vre0, float& vim0, float& vre1, float& vim1,
    float& vre2, float& vim2, float& vre3, float& vim3) {
  if (!odd) {
    float nr0 = qa.x * vre0 - qa.y * vim0 + qa.z * vre1 - qa.w * vim1;
    float ni0 = qa.x * vim0 + qa.y * vre0 + qa.z * vim1 + qa.w * vre1;
    float nr1 = cc.x * vre1 - cc.y * vre0;
    float ni1 = cc.x * vim1 - cc.y * vim0;
    float nr2 = qb.x * vre2 - qb.y * vim2 + qb.z * vre3 - qb.w * vim3;
    float ni2 = qb.x * vim2 + qb.y * vre2 + qb.z * vim3 + qb.w * vre3;
    float nr3 = cc.z * vre3 - cc.w * vre2;
    float ni3 = cc.z * vim3 - cc.w * vim2;
    vre0 = nr0; vim0 = ni0; vre1 = nr1; vim1 = ni1;
    vre2 = nr2; vim2 = ni2; vre3 = nr3; vim3 = ni3;
  } else {
    int nxt = (lane + 1) & 63, prv = (lane + 63) & 63;
    float xre = __shfl(vre0, nxt, 64);
    float xim = __shfl(vim0, nxt, 64);
    float pre = __shfl(vre3, prv, 64);
    float pim = __shfl(vim3, prv, 64);
    float cp  = __shfl(cc.z, prv, 64);
    float sp  = __shfl(cc.w, prv, 64);
    float nr1 = qa.x * vre1 - qa.y * vim1 + qa.z * vre2 - qa.w * vim2;
    float ni1 = qa.x * vim1 + qa.y * vre1 + qa.z * vim2 + qa.w * vre2;
    float nr2 = cc.x * vre2 - cc.y * vre1;
    float ni2 = cc.x * vim2 - cc.y * vim1;
    float nr3 = qb.x * vre3 - qb.y * vim3 + qb.z * xre - qb.w * xim;
    float ni3 = qb.x * vim3 + qb.y * vre3 + qb.z * xim + qb.w * xre;
    float nr0 = cp * vre0 - sp * pre;
    float ni0 = cp * vim0 - sp * pim;
    vre0 = nr0; vim0 = ni0; vre1 = nr1; vim1 = ni1;
    vre2 = nr2; vim2 = ni2; vre3 = nr3; vim3 = ni3;
  }
}

template<bool TBL>
__global__ __launch_bounds__(256) void olk_build(
    const float* __restrict__ theta, const float* __restrict__ phi,
    const float* __restrict__ outph,
    const float4* __restrict__ t4, const float2* __restrict__ t2,
    __bf16* __restrict__ Tb2) {
  int lane = threadIdx.x & 63;
  int r = blockIdx.x * 4 + (threadIdx.x >> 6);
  int c0 = lane * 4;
  float vre0 = (c0 + 0 == r) ? 1.f : 0.f, vim0 = 0.f;
  float vre1 = (c0 + 1 == r) ? 1.f : 0.f, vim1 = 0.f;
  float vre2 = (c0 + 2 == r) ? 1.f : 0.f, vim2 = 0.f;
  float vre3 = (c0 + 3 == r) ? 1.f : 0.f, vim3 = 0.f;

  P8 A, B;
  loadP8<TBL>(A, 31 * 8, lane, t4, t2, theta, phi);
  for (int it = 0; it < 16; ++it) {
    int bA = 31 - 2 * it;
    int bB = bA - 1;
    loadP8<TBL>(B, bB * 8, lane, t4, t2, theta, phi);
#pragma unroll
    for (int k = 7; k >= 0; --k)
      layer_step((k & 1) != 0, lane, A.qa[k], A.qb[k], A.cc[k],
                 vre0, vim0, vre1, vim1, vre2, vim2, vre3, vim3);
    if (it < 15)
      loadP8<TBL>(A, (bB - 1) * 8, lane, t4, t2, theta, phi);
#pragma unroll
    for (int k = 7; k >= 0; --k)
      layer_step((k & 1) != 0, lane, B.qa[k], B.qb[k], B.cc[k],
                 vre0, vim0, vre1, vim1, vre2, vim2, vre3, vim3);
  }

  float oph = outph[r];
  float co = cosf(oph), so = sinf(oph);
  bf16x4 o;
  o[0] = to_bf16(co * vre0 - so * vim0);
  o[1] = to_bf16(co * vre1 - so * vim1);
  o[2] = to_bf16(co * vre2 - so * vim2);
  o[3] = to_bf16(co * vre3 - so * vim3);

  // Fragment-ordered store: B-frag (8 bf16) for (row, ks, lg) is contiguous
  // 16B at r*256 + ks*32 + lg*8.
  int ks = lane >> 3, sub = lane & 7;
  int pos = ks * 32 + (sub & 3) * 8 + (sub >> 2) * 4;
  *(bf16x4*)(Tb2 + r * 256 + pos) = o;
}

// ---------------------------------------------------------------------------
// Matmul: out[131072][64] = x[131072][256] @ T[64][256]^T, bf16 MFMA 16x16x32.
// In-flight-decoupled design: 1 wave per block, private 2x16KB LDS ring,
// global_load_lds staging (async DMA: bytes-in-flight cost ZERO VGPRs),
// counted vmcnt(16) (never 0), NO barriers (single wave owns its ring ->
// its own vmcnt is full synchronization). 1280 blocks x 6-7 tiles grid-
// stride; 5 blocks/CU x 16KB perpetually outstanding = ~80KB/CU in flight
// (roofline needs ~20KB). B = 128 VGPRs/wave, full N=64, zero redundancy.
// Stage: 16 x 1KB contiguous (lane-linear) with XOR-swizzled global src;
// ds_read_b128 applies same XOR -> balanced 8 words/bank (b128 optimum).
// ---------------------------------------------------------------------------
#define NTILES 8192
#define NBLK   1280
#define TQ     6          // NTILES / NBLK
#define TAILB  512        // NTILES - NBLK*TQ

__global__ __launch_bounds__(64) void olk_mm(
    const float* __restrict__ x, const __bf16* __restrict__ Tb2,
    float* __restrict__ out) {
  __shared__ float4 sb[2][1024];            // 2 slots x 16KB
  int lane = threadIdx.x;                   // 0..63
  int l15 = lane & 15, lg = lane >> 4, sw = l15 & 7;

  // B fragments in registers: 32 x bf16x8 = 128 VGPR (frag-ordered Tb2)
  bf16x8 b[8][4];
#pragma unroll
  for (int ks = 0; ks < 8; ++ks)
#pragma unroll
    for (int nt = 0; nt < 4; ++nt)
      b[ks][nt] = *(const bf16x8*)(Tb2 + (nt * 16 + l15) * 256 + ks * 32 + lg * 8);
  asm volatile("s_waitcnt vmcnt(0)" ::: "memory");   // clean vmcnt state

  int bid = blockIdx.x;
  int start, cnt;
  if (bid < TAILB) { start = bid * (TQ + 1); cnt = TQ + 1; }
  else             { start = TAILB * (TQ + 1) + (bid - TAILB) * TQ; cnt = TQ; }

  // stage tile -> slot: 16 async 1KB loads; global chunk = lane ^ (row&7)
  // (inverse swizzle on src side; LDS dest linear as HW requires)
  auto stage = [&](int slot, int tile) {
    const float* base = x + ((size_t)tile << 12);
#pragma unroll
    for (int i = 0; i < 16; ++i) {
      const float* src = base + i * 256 + ((lane ^ (i & 7)) << 2);
      GLD_LDS16(src, &sb[slot][i * 64]);
    }
  };

  stage(0, start);
#pragma unroll 1
  for (int t = 0; t < cnt; ++t) {
    if (t + 1 < cnt) stage((t + 1) & 1, start + t + 1);
    // oldest-drain: leaves the 16 newest (next tile's loads / last stores)
    // outstanding; guarantees tile t's 16 loads have landed.
    asm volatile("s_waitcnt vmcnt(16)" ::: "memory");

    const float4* A = sb[t & 1];
    f32x4 acc[4];
#pragma unroll
    for (int nt = 0; nt < 4; ++nt) acc[nt] = (f32x4){0.f, 0.f, 0.f, 0.f};

#pragma unroll
    for (int ks = 0; ks < 8; ++ks) {
      float4 lo = A[l15 * 64 + ((ks * 8 + lg) ^ sw)];
      float4 hi = A[l15 * 64 + ((ks * 8 + lg + 4) ^ sw)];
      bf16x8 v;
      v[0] = to_bf16(lo.x); v[1] = to_bf16(lo.y);
      v[2] = to_bf16(lo.z); v[3] = to_bf16(lo.w);
      v[4] = to_bf16(hi.x); v[5] = to_bf16(hi.y);
      v[6] = to_bf16(hi.z); v[7] = to_bf16(hi.w);
#pragma unroll
      for (int nt = 0; nt < 4; ++nt)
        acc[nt] = __builtin_amdgcn_mfma_f32_16x16x32_bf16(v, b[ks][nt], acc[nt], 0, 0, 0);
    }

    float* ob = out + ((size_t)(start + t) * 16) * 64 + l15;
#pragma unroll
    for (int r = 0; r < 4; ++r)
#pragma unroll
      for (int nt = 0; nt < 4; ++nt)     // 64B contiguous per (r,nt) segment
        ob[(4 * lg + r) * 64 + nt * 16] = acc[nt][r];
  }
}

// ---------------------------------------------------------------------------
extern "C" void kernel_launch(void* const* d_in, const int* in_sizes, int n_in,
                              void* d_out, int out_size, void* d_ws, size_t ws_size,
                              hipStream_t stream) {
  const float* x     = (const float*)d_in[0];
  const float* theta = (const float*)d_in[1];
  const float* phi   = (const float*)d_in[2];
  const float* outph = (const float*)d_in[3];
  float* out = (float*)d_out;

  char* ws = (char*)d_ws;
  bool tbl = ws_size >= (size_t)(832 * 1024);
  float4* t4 = (float4*)ws;                       // 512 KB
  float2* t2 = (float2*)(ws + 512 * 1024);        // 256 KB
  __bf16* Tb2 = (__bf16*)(ws + (tbl ? 768 * 1024 : 0));  // 32 KB frag-ordered T

  if (tbl) {
    olk_params<<<128, 256, 0, stream>>>(theta, phi, t4, t2);
    olk_build<true><<<16, 256, 0, stream>>>(theta, phi, outph, t4, t2, Tb2);
  } else {
    olk_build<false><<<16, 256, 0, stream>>>(theta, phi, outph, nullptr, nullptr, Tb2);
  }
  olk_mm<<<NBLK, 64, 0, stream>>>(x, Tb2, out);
}